// Round 15
// baseline (252.479 us; speedup 1.0000x reference)
//
#include <hip/hip_runtime.h>

#define S_LEN 2048
#define B_SZ 2
#define DMODEL 2048
#define NHEADS 16
#define NKV 4
#define DHEAD 128
#define SCALE 0.08838834764831845f  // 1/sqrt(128)
#define KVB 64

typedef __bf16 bf16x8 __attribute__((ext_vector_type(8)));
typedef __bf16 bf16x4 __attribute__((ext_vector_type(4)));
typedef float f32x4 __attribute__((ext_vector_type(4)));

#define MFMA(a, b, c) __builtin_amdgcn_mfma_f32_16x16x32_bf16(a, b, c, 0, 0, 0)

__device__ __forceinline__ void gload_lds16(const __bf16* g, __bf16* l) {
    __builtin_amdgcn_global_load_lds(
        (const __attribute__((address_space(1))) unsigned int*)g,
        (__attribute__((address_space(3))) unsigned int*)l, 16, 0, 0);
}

// ---------------------------------------------------------------------------
// fp32 -> bf16 convert (5 regions) + RoPE tables (region 5).
// grid (512, 6) x 256 threads.
// ---------------------------------------------------------------------------
__global__ __launch_bounds__(256) void convert_kernel(
    const float* __restrict__ s0, const float* __restrict__ s1,
    const float* __restrict__ s2, const float* __restrict__ s3,
    const float* __restrict__ s4,
    __bf16* __restrict__ d0, __bf16* __restrict__ d1, __bf16* __restrict__ d2,
    __bf16* __restrict__ d3, __bf16* __restrict__ d4,
    float* __restrict__ cosT, float* __restrict__ sinT) {
    if (blockIdx.y == 5) {
        int i = blockIdx.x * 256 + threadIdx.x;   // 512*256 == S*64 exactly
        int s = i >> 6, d = i & 63;
        float freq = powf(10000.0f, -(2.0f * (float)d) / 128.0f);
        float ang = (float)s * freq;
        cosT[i] = cosf(ang);
        sinT[i] = sinf(ang);
        return;
    }
    const float* s;
    __bf16* d;
    int n8;
    switch (blockIdx.y) {
        case 0: s = s0; d = d0; n8 = (B_SZ * S_LEN * DMODEL) / 8; break;      // qkv
        case 1: s = s1; d = d1; n8 = (DMODEL * DMODEL) / 8; break;            // Wq
        case 2: s = s2; d = d2; n8 = (NKV * DHEAD * DMODEL) / 8; break;       // Wk
        case 3: s = s3; d = d3; n8 = (NKV * DHEAD * DMODEL) / 8; break;       // Wv
        default: s = s4; d = d4; n8 = (DMODEL * DMODEL) / 8; break;           // Wo
    }
    for (int i = blockIdx.x * 256 + threadIdx.x; i < n8; i += 512 * 256) {
        float4 a = ((const float4*)s)[2 * i];
        float4 b = ((const float4*)s)[2 * i + 1];
        bf16x8 o = {(__bf16)a.x, (__bf16)a.y, (__bf16)a.z, (__bf16)a.w,
                    (__bf16)b.x, (__bf16)b.y, (__bf16)b.z, (__bf16)b.w};
        *(bf16x8*)&d[i * 8] = o;
    }
}

// ---------------------------------------------------------------------------
// 256-wide-tile GEMM mainloop, BK=64, 8 waves (2M x 4N), counted-vmcnt
// prefetch (distance 2), T2 XOR-swizzled LDS, 4-phase per-tile schedule.
// ---------------------------------------------------------------------------
template <int BM>
__device__ __forceinline__ void gemm256(const __bf16* __restrict__ A,
                                        const __bf16* __restrict__ W,
                                        int bm, int bn, int K,
                                        f32x4 (&acc)[BM / 32][4],
                                        __bf16* arena) {
    constexpr int MI = BM / 32;       // 8 (qkv) or 4 (out_proj)
    constexpr int ALT = BM / 64;      // stageA issues per thread
    constexpr int QM = MI / 4;        // mi per quad: 2 or 1
    __bf16* As = arena;                      // [2][BM*64]
    __bf16* Bs = arena + 2 * BM * 64;        // [2][256*64]
    const int tid = threadIdx.x;
    const int lane = tid & 63;
    const int wave = tid >> 6;
    const int lr = lane & 15, lk = lane >> 4;
    const int wr = wave >> 2;
    const int wc = wave & 3;
    const int sRow = lane >> 3;
    const int sCol = 8 * ((lane & 7) ^ sRow);

    auto stageA = [&](int bi, int k0) {
#pragma unroll
        for (int it = 0; it < ALT; ++it) {
            const int row = it * 64 + wave * 8 + sRow;
            gload_lds16(A + (size_t)(bm + row) * K + k0 + sCol,
                        As + bi * BM * 64 + it * 4096 + wave * 512);
        }
    };
    auto stageB = [&](int bi, int k0) {
#pragma unroll
        for (int it = 0; it < 4; ++it) {
            const int row = it * 64 + wave * 8 + sRow;
            gload_lds16(W + (size_t)(bn + row) * K + k0 + sCol,
                        Bs + bi * 16384 + it * 4096 + wave * 512);
        }
    };

#pragma unroll
    for (int mi = 0; mi < MI; ++mi)
#pragma unroll
        for (int ni = 0; ni < 4; ++ni) acc[mi][ni] = (f32x4){0.f, 0.f, 0.f, 0.f};

    const int NT = K >> 6;
    stageA(0, 0);
    stageB(0, 0);
    stageA(1, 64);
    stageB(1, 64);
    if constexpr (BM == 256) asm volatile("s_waitcnt vmcnt(8)" ::: "memory");
    else                     asm volatile("s_waitcnt vmcnt(6)" ::: "memory");
    __builtin_amdgcn_s_barrier();

    for (int t = 0; t < NT; ++t) {
        const int bi = t & 1;
        bf16x8 af[MI][2], bfr[4][2];
        auto rdA = [&](int i, int kk) {
            const int r = wr * (BM / 2) + i * 16 + lr;
            const int slot = (kk * 4 + lk) ^ (r & 7);
            af[i][kk] = *(const bf16x8*)&As[bi * BM * 64 + r * 64 + slot * 8];
        };
        auto quad = [&](int q) {
            __builtin_amdgcn_s_setprio(1);
#pragma unroll
            for (int mi = q * QM; mi < (q + 1) * QM; ++mi)
#pragma unroll
                for (int kk = 0; kk < 2; ++kk)
#pragma unroll
                    for (int ni = 0; ni < 4; ++ni)
                        acc[mi][ni] = MFMA(af[mi][kk], bfr[ni][kk], acc[mi][ni]);
            __builtin_amdgcn_s_setprio(0);
        };

        // ---- ph0: all B frags + quad0's A frags
#pragma unroll
        for (int i = 0; i < 4; ++i)
#pragma unroll
            for (int kk = 0; kk < 2; ++kk) {
                const int r = wc * 64 + i * 16 + lr;
                const int slot = (kk * 4 + lk) ^ (r & 7);
                bfr[i][kk] = *(const bf16x8*)&Bs[bi * 16384 + r * 64 + slot * 8];
            }
#pragma unroll
        for (int i = 0; i < QM; ++i)
#pragma unroll
            for (int kk = 0; kk < 2; ++kk) rdA(i, kk);
        __builtin_amdgcn_s_barrier();
        asm volatile("s_waitcnt lgkmcnt(0)" ::: "memory");
        __builtin_amdgcn_sched_barrier(0);
        quad(0);
        __builtin_amdgcn_s_barrier();

        // ---- ph1: remaining A frags
#pragma unroll
        for (int i = QM; i < MI; ++i)
#pragma unroll
            for (int kk = 0; kk < 2; ++kk) rdA(i, kk);
        __builtin_amdgcn_s_barrier();
        asm volatile("s_waitcnt lgkmcnt(0)" ::: "memory");
        __builtin_amdgcn_sched_barrier(0);
        quad(1);
        __builtin_amdgcn_s_barrier();
        // all waves' reads of buf[bi] are complete past this point

        // ---- ph2: stage A of tile t+2 into buf[bi]  ||  quad2 (regs only)
        if (t + 2 < NT) stageA(bi, (t + 2) * 64);
        quad(2);
        __builtin_amdgcn_s_barrier();

        // ---- ph3: stage B of tile t+2  ||  quad3; then publish t+1
        if (t + 2 < NT) stageB(bi, (t + 2) * 64);
        quad(3);
        if (t + 1 < NT) {
            if (t + 2 < NT) {
                if constexpr (BM == 256) asm volatile("s_waitcnt vmcnt(8)" ::: "memory");
                else                     asm volatile("s_waitcnt vmcnt(6)" ::: "memory");
            } else {
                asm volatile("s_waitcnt vmcnt(0)" ::: "memory");
            }
            __builtin_amdgcn_s_barrier();  // buf[(t+1)&1] ready for everyone
        }
    }
}

// ---------------------------------------------------------------------------
// Fused QKV projection: 256^2 GEMM + RMSNorm + RoPE (+SCALE for Q) + direct
// bf16 layout transforms.  grid 192 blocks (XCD-remapped), 512 threads.
// ---------------------------------------------------------------------------
__global__ __launch_bounds__(512, 2) void qkv_proj_kernel(
    const __bf16* __restrict__ qkvb, const __bf16* __restrict__ Wq,
    const __bf16* __restrict__ Wk, const __bf16* __restrict__ Wv,
    const float* __restrict__ qg, const float* __restrict__ kg,
    const float* __restrict__ cosT, const float* __restrict__ sinT,
    __bf16* __restrict__ qb, __bf16* __restrict__ kb, __bf16* __restrict__ vt) {
    __shared__ alignas(16) __bf16 arena[4 * 256 * 64];   // 128 KB
    const int id = (blockIdx.x & 7) * 24 + (blockIdx.x >> 3);  // bijective 192=8*24
    const int bmi = id / 12, bni = id % 12;
    const int bm = bmi * 256;
    const __bf16* W;
    int bn;
    if (bni < 8)       { W = Wq; bn = bni * 256; }
    else if (bni < 10) { W = Wk; bn = (bni - 8) * 256; }
    else               { W = Wv; bn = (bni - 10) * 256; }

    f32x4 acc[8][4];
    gemm256<256>(qkvb, W, bm, bn, 2048, acc, arena);
    // mainloop's final s_barrier synchronized all waves; arena is reusable.

    const int tid = threadIdx.x;
    const int lane = tid & 63, wave = tid >> 6;
    const int lr = lane & 15, lk = lane >> 4;
    const int wr = wave >> 2, wc = wave & 3;
    const int dc0 = (wc & 1) * 64;          // this wave's dcol base in head

    if (bni < 10) {
        // ---- Q or K: RMSNorm + RoPE ----
        const bool isQ = (bni < 8);
        const float* gamma = isQ ? qg : kg;
        const float scl = isQ ? SCALE : 1.0f;
        const int hh = (isQ ? bni * 2 : (bni - 8) * 2) + (wc >> 1);
        const int nh = isQ ? NHEADS : NKV;
        __bf16* outb = isQ ? qb : kb;
        float g[4];
#pragma unroll
        for (int ni = 0; ni < 4; ++ni) g[ni] = gamma[dc0 + ni * 16 + lr];

        float* xbuf = (float*)arena;                       // [512][33] = 67.6KB
        float* ssbuf = (float*)((char*)arena + 70 * 1024); // [4][256] = 4KB

        // Phase A: per-row sum of squares (64-col partial -> pair total)
        float rs[8][4];
#pragma unroll
        for (int mi = 0; mi < 8; ++mi)
#pragma unroll
            for (int r = 0; r < 4; ++r) {
                float ss = 0.f;
#pragma unroll
                for (int ni = 0; ni < 4; ++ni) ss += acc[mi][ni][r] * acc[mi][ni][r];
                ss += __shfl_xor(ss, 1);
                ss += __shfl_xor(ss, 2);
                ss += __shfl_xor(ss, 4);
                ss += __shfl_xor(ss, 8);
                if (lr == 0) ssbuf[wc * 256 + wr * 128 + mi * 16 + lk * 4 + r] = ss;
            }
        __syncthreads();
#pragma unroll
        for (int mi = 0; mi < 8; ++mi)
#pragma unroll
            for (int r = 0; r < 4; ++r) {
                const int rowl = wr * 128 + mi * 16 + lk * 4 + r;
                const float tot = ssbuf[wc * 256 + rowl] + ssbuf[(wc ^ 1) * 256 + rowl];
                rs[mi][r] = rsqrtf(tot * (1.0f / 128.0f) + 1e-6f) * scl;
            }
        __syncthreads();   // ssbuf reads done before xbuf writes (overlap-safe)

        // Phase B: chunked pair-exchange of normalized values + RoPE + store.
#pragma unroll
        for (int ch = 0; ch < 4; ++ch) {
            float y[2][4][4];
#pragma unroll
            for (int m2 = 0; m2 < 2; ++m2)
#pragma unroll
                for (int ni = 0; ni < 4; ++ni)
#pragma unroll
                    for (int r = 0; r < 4; ++r) {
                        const int mi = ch * 2 + m2;
                        y[m2][ni][r] = acc[mi][ni][r] * rs[mi][r] * g[ni];
                        xbuf[tid * 33 + m2 * 16 + ni * 4 + r] = y[m2][ni][r];
                    }
            __syncthreads();
            float yp[2][4][4];
#pragma unroll
            for (int m2 = 0; m2 < 2; ++m2)
#pragma unroll
                for (int ni = 0; ni < 4; ++ni)
#pragma unroll
                    for (int r = 0; r < 4; ++r)
                        yp[m2][ni][r] = xbuf[(tid ^ 64) * 33 + m2 * 16 + ni * 4 + r];
#pragma unroll
            for (int m2 = 0; m2 < 2; ++m2)
#pragma unroll
                for (int r = 0; r < 4; ++r) {
                    const int mi = ch * 2 + m2;
                    const int gm = bm + wr * 128 + mi * 16 + lk * 4 + r;
                    const int bb = gm >> 11, s = gm & 2047;
                    const float* ct = cosT + s * 64;
                    const float* st = sinT + s * 64;
                    __bf16* orow = outb + (((size_t)(bb * nh + hh)) * S_LEN + s) * DHEAD;
#pragma unroll
                    for (int ni = 0; ni < 4; ++ni) {
                        const int dd = ni * 16 + lr;
                        const float c = ct[dd], sn = st[dd];
                        const float own = y[m2][ni][r], par = yp[m2][ni][r];
                        const float o = (wc & 1) ? (own * c + par * sn)
                                                 : (own * c - par * sn);
                        orow[dc0 + dd] = (__bf16)o;
                    }
                }
            __syncthreads();   // xbuf consumed before next chunk overwrites
        }
    } else {
        // ---- V: write transposed bf16 directly into vt [B,KV,Dh,S] ----
        const int kvh = (bni - 10) * 2 + (wc >> 1);
#pragma unroll
        for (int mi = 0; mi < 8; ++mi) {
            const int gm = bm + wr * 128 + mi * 16 + lk * 4;  // 4 consecutive s
            const int bb = gm >> 11, s0 = gm & 2047;
            __bf16* vbase = vt + ((size_t)(bb * NKV + kvh)) * DHEAD * S_LEN;
#pragma unroll
            for (int ni = 0; ni < 4; ++ni) {
                const int d = dc0 + ni * 16 + lr;
                bf16x4 pk = {(__bf16)acc[mi][ni][0], (__bf16)acc[mi][ni][1],
                             (__bf16)acc[mi][ni][2], (__bf16)acc[mi][ni][3]};
                *(bf16x4*)&vbase[(size_t)d * S_LEN + s0] = pk;
            }
        }
    }
}

// ---------------------------------------------------------------------------
// Output projection.  1D grid of 256 blocks (XCD-remapped), 512 threads.
// ---------------------------------------------------------------------------
__global__ __launch_bounds__(512, 2) void out_proj_kernel(
    const __bf16* __restrict__ att, const __bf16* __restrict__ Wo,
    float* __restrict__ out) {
    __shared__ alignas(16) __bf16 arena[2 * 128 * 64 + 2 * 256 * 64];  // 96 KB
    const int id = (blockIdx.x & 7) * 32 + (blockIdx.x >> 3);  // bijective 256=8*32
    const int bm = (id >> 3) * 128, bn = (id & 7) * 256;

    f32x4 acc[4][4];
    gemm256<128>(att, Wo, bm, bn, 2048, acc, arena);

    const int lane = threadIdx.x & 63, wave = threadIdx.x >> 6;
    const int lr = lane & 15, lk = lane >> 4;
    const int wr = wave >> 2, wc = wave & 3;
#pragma unroll
    for (int mi = 0; mi < 4; ++mi)
#pragma unroll
        for (int ni = 0; ni < 4; ++ni)
#pragma unroll
            for (int r = 0; r < 4; ++r) {
                const int row = bm + wr * 64 + mi * 16 + lk * 4 + r;
                const int col = bn + wc * 64 + ni * 16 + lr;
                out[(size_t)row * DMODEL + col] = acc[mi][ni][r];
            }
}

// ---------------------------------------------------------------------------
// Causal flash attention, round-13 structure with KVB=64 tiles:
// half the tiles (barriers/drains per key halved), 16-MFMA QK and PV
// clusters per frag_step.  grid (B*H, 16), 256 threads = 4 waves.
// K_lds [64][128] (256B rows, byte^=(row&7)<<4); V_lds [128][64] (128B rows,
// byte^=(row&7)<<4); p_lds rows 144B (4-bank rotation, 2-way = free).
// ---------------------------------------------------------------------------
__global__ __launch_bounds__(256, 2) void flash_kernel(
    const __bf16* __restrict__ qb, const __bf16* __restrict__ kb,
    const __bf16* __restrict__ vt, __bf16* __restrict__ att) {
    __shared__ alignas(16) __bf16 K_lds[2][64 * 128];   // 16KB each
    __shared__ alignas(16) __bf16 V_lds[2][128 * 64];   // 16KB each
    __shared__ alignas(16) __bf16 p_lds[4][16][72];     // per-wave, 144B rows

    const int bh = blockIdx.x;
    const int b = bh >> 4, h = bh & 15, kv = h >> 2;
    const int j = blockIdx.y;  // 0..15
    const int lane = threadIdx.x & 63, wave = threadIdx.x >> 6;
    const int lr = lane & 15, lk = lane >> 4;

    const int qloB = j * 64 + wave * 16;
    const int qhiB = (31 - j) * 64 + wave * 16;
    const int ntL  = (qloB >> 6) + 1;   // per-wave low-frag KV64 tiles
    const int ntHw = (qhiB >> 6) + 1;   // per-wave high-frag KV64 tiles
    const int ntH  = 32 - j;            // block-uniform staged tiles

    const __bf16* Qp = qb + ((size_t)(b * NHEADS + h)) * S_LEN * DHEAD;
    const __bf16* Kp = kb + ((size_t)(b * NKV + kv)) * S_LEN * DHEAD;
    const __bf16* Vt = vt + ((size_t)(b * NKV + kv)) * DHEAD * S_LEN;

    bf16x8 qlo[4], qhi[4];
#pragma unroll
    for (int f = 0; f < 4; ++f) {
        qlo[f] = *(const bf16x8*)&Qp[(size_t)(qloB + lr) * DHEAD + f * 32 + lk * 8];
        qhi[f] = *(const bf16x8*)&Qp[(size_t)(qhiB + lr) * DHEAD + f * 32 + lk * 8];
    }

    // staging lane constants (inverse-swizzled global source)
    const int l15 = lane & 15, l4 = lane >> 4;
    const int l8 = lane >> 3, l7 = lane & 7;

    auto stage = [&](int bufi, int t) {
        const int k0s = t * KVB;
#pragma unroll
        for (int i = 0; i < 4; ++i) {
            const int c = wave * 4 + i;           // chunk 0..15 (1KB each)
            // K: 4 rows of 256B per chunk
            const int rK = c * 4 + l4;
            const int kcol = ((l15 ^ (rK & 7)) << 3);
            gload_lds16(Kp + (size_t)(k0s + rK) * DHEAD + kcol, &K_lds[bufi][c * 512]);
            // V: 8 rows of 128B per chunk
            const int rV = c * 8 + l8;
            const int vcol = ((l7 ^ (rV & 7)) << 3);
            gload_lds16(Vt + (size_t)rV * S_LEN + k0s + vcol, &V_lds[bufi][c * 512]);
        }
    };

    f32x4 accL[8] = {}, accH[8] = {};
    float lsumL[4] = {0.f, 0.f, 0.f, 0.f}, lsumH[4] = {0.f, 0.f, 0.f, 0.f};
    const int swz = (lr & 7) << 4;

    auto frag_step = [&](const bf16x8 (&qf)[4], int qbase, f32x4 (&acc)[8],
                         float (&lsum)[4], const bf16x8 (&kf)[4][4],
                         const bf16x8 (&vf)[8][2], int k0) {
        f32x4 sc[4] = {};
        __builtin_amdgcn_s_setprio(1);
#pragma unroll
        for (int kk = 0; kk < 4; ++kk)
#pragma unroll
            for (int f = 0; f < 4; ++f)
                sc[kk] = MFMA(qf[f], kf[kk][f], sc[kk]);
        __builtin_amdgcn_s_setprio(0);
        // prior p_lds reads (this wave) must complete before overwrite
        asm volatile("s_waitcnt lgkmcnt(0)" ::: "memory");
#pragma unroll
        for (int r = 0; r < 4; ++r) {
            const int qr = qbase + lk * 4 + r;
#pragma unroll
            for (int kk = 0; kk < 4; ++kk) {
                float s0 = sc[kk][r];
                if (k0 + kk * 16 + lr > qr) s0 = -1e30f;
                float p0 = __expf(s0);
                lsum[r] += p0;
                p_lds[wave][lk * 4 + r][kk * 16 + lr] = (__bf16)p0;
            }
        }
        asm volatile("s_waitcnt lgkmcnt(0)" ::: "memory");
        bf16x8 pf0 = *(const bf16x8*)&p_lds[wave][lr][lk * 8];
        bf16x8 pf1 = *(const bf16x8*)&p_lds[wave][lr][32 + lk * 8];
        __builtin_amdgcn_s_setprio(1);
#pragma unroll
        for (int nf = 0; nf < 8; ++nf) {
            acc[nf] = MFMA(pf0, vf[nf][0], acc[nf]);
            acc[nf] = MFMA(pf1, vf[nf][1], acc[nf]);
        }
        __builtin_amdgcn_s_setprio(0);
    };

    int cur = 0;
    stage(0, 0);
    __syncthreads();   // drains stage vmcnt before first use
    for (int t = 0; t < ntH; ++t) {
        if (t + 1 < ntH) stage(cur ^ 1, t + 1);
        const int k0 = t * KVB;
        bf16x8 kf[4][4], vf[8][2];
#pragma unroll
        for (int kk = 0; kk < 4; ++kk)
#pragma unroll
            for (int f = 0; f < 4; ++f) {
                const int row = kk * 16 + lr;
                const int cb = (f * 64 + lk * 16) ^ ((row & 7) << 4);
                kf[kk][f] = *(const bf16x8*)((const char*)&K_lds[cur][row * 128] + cb);
            }
#pragma unroll
        for (int nf = 0; nf < 8; ++nf)
#pragma unroll
            for (int ks = 0; ks < 2; ++ks) {
                const int row = nf * 16 + lr;
                const int cb = (ks * 64 + lk * 16) ^ ((row & 7) << 4);
                vf[nf][ks] = *(const bf16x8*)((const char*)&V_lds[cur][row * 64] + cb);
            }
        if (t < ntHw) frag_step(qhi, qhiB, accH, lsumH, kf, vf, k0);
        if (t < ntL)  frag_step(qlo, qloB, accL, lsumL, kf, vf, k0);
        __syncthreads();   // all waves done with buf[cur]; next stage reuses it
        cur ^= 1;
    }

#pragma unroll
    for (int r = 0; r < 4; ++r) {
#pragma unroll
        for (int m = 1; m < 16; m <<= 1) {
            lsumL[r] += __shfl_xor(lsumL[r], m);
            lsumH[r] += __shfl_xor(lsumH[r], m);
        }
    }
#pragma unroll
    for (int nf = 0; nf < 8; ++nf)
#pragma unroll
        for (int r = 0; r < 4; ++r) {
            int qrL = qloB + lk * 4 + r;
            int qrH = qhiB + lk * 4 + r;
            att[((size_t)(b * S_LEN) + qrL) * DMODEL + h * DHEAD + nf * 16 + lr] =
                (__bf16)(accL[nf][r] / lsumL[r]);
            att[((size_t)(b * S_LEN) + qrH) * DMODEL + h * DHEAD + nf * 16 + lr] =
                (__bf16)(accH[nf][r] / lsumH[r]);
        }
}

// ---------------------------------------------------------------------------
extern "C" void kernel_launch(void* const* d_in, const int* in_sizes, int n_in,
                              void* d_out, int out_size, void* d_ws, size_t ws_size,
                              hipStream_t stream) {
    const float* qkv = (const float*)d_in[0];
    const float* Wq  = (const float*)d_in[1];
    const float* Wk  = (const float*)d_in[2];
    const float* Wv  = (const float*)d_in[3];
    const float* Wo  = (const float*)d_in[4];
    const float* qg  = (const float*)d_in[5];
    const float* kg  = (const float*)d_in[6];
    float* out = (float*)d_out;

    size_t off = 0;
    char* wsb = (char*)d_ws;
    auto alloc = [&](size_t n) {
        char* p = wsb + off;
        off += (n + 255) & ~(size_t)255;
        return (void*)p;
    };
    const size_t M = (size_t)B_SZ * S_LEN;  // 4096
    float* cosT   = (float*)alloc((size_t)S_LEN * 64 * 4);
    float* sinT   = (float*)alloc((size_t)S_LEN * 64 * 4);
    __bf16* qb    = (__bf16*)alloc((size_t)B_SZ * NHEADS * S_LEN * DHEAD * 2);
    __bf16* kb    = (__bf16*)alloc((size_t)B_SZ * NKV * S_LEN * DHEAD * 2);
    __bf16* vt    = (__bf16*)alloc((size_t)B_SZ * NKV * DHEAD * S_LEN * 2);
    __bf16* att   = (__bf16*)alloc(M * DMODEL * 2);
    __bf16* qkv_b = (__bf16*)alloc(M * DMODEL * 2);
    __bf16* wq_b  = (__bf16*)alloc((size_t)DMODEL * DMODEL * 2);
    __bf16* wk_b  = (__bf16*)alloc((size_t)NKV * DHEAD * DMODEL * 2);
    __bf16* wv_b  = (__bf16*)alloc((size_t)NKV * DHEAD * DMODEL * 2);
    __bf16* wo_b  = (__bf16*)alloc((size_t)DMODEL * DMODEL * 2);

    convert_kernel<<<dim3(512, 6), 256, 0, stream>>>(qkv, Wq, Wk, Wv, Wo,
                                                     qkv_b, wq_b, wk_b, wv_b, wo_b,
                                                     cosT, sinT);
    qkv_proj_kernel<<<192, 512, 0, stream>>>(qkv_b, wq_b, wk_b, wv_b,
                                             qg, kg, cosT, sinT, qb, kb, vt);
    flash_kernel<<<dim3(B_SZ * NHEADS, 16), 256, 0, stream>>>(qb, kb, vt, att);
    out_proj_kernel<<<256, 512, 0, stream>>>(att, wo_b, out);
}

// Round 16
// 185.574 us; speedup vs baseline: 1.3605x; 1.3605x over previous
//
#include <hip/hip_runtime.h>

#define S_LEN 2048
#define B_SZ 2
#define DMODEL 2048
#define NHEADS 16
#define NKV 4
#define DHEAD 128
#define SCALE 0.08838834764831845f  // 1/sqrt(128)
#define KVB 32

typedef __bf16 bf16x8 __attribute__((ext_vector_type(8)));
typedef __bf16 bf16x4 __attribute__((ext_vector_type(4)));
typedef float f32x4 __attribute__((ext_vector_type(4)));

#define MFMA(a, b, c) __builtin_amdgcn_mfma_f32_16x16x32_bf16(a, b, c, 0, 0, 0)

__device__ __forceinline__ void gload_lds16(const __bf16* g, __bf16* l) {
    __builtin_amdgcn_global_load_lds(
        (const __attribute__((address_space(1))) unsigned int*)g,
        (__attribute__((address_space(3))) unsigned int*)l, 16, 0, 0);
}

// ---------------------------------------------------------------------------
// fp32 -> bf16 convert (5 regions) + RoPE tables (region 5).
// grid (512, 6) x 256 threads.
// ---------------------------------------------------------------------------
__global__ __launch_bounds__(256) void convert_kernel(
    const float* __restrict__ s0, const float* __restrict__ s1,
    const float* __restrict__ s2, const float* __restrict__ s3,
    const float* __restrict__ s4,
    __bf16* __restrict__ d0, __bf16* __restrict__ d1, __bf16* __restrict__ d2,
    __bf16* __restrict__ d3, __bf16* __restrict__ d4,
    float* __restrict__ cosT, float* __restrict__ sinT) {
    if (blockIdx.y == 5) {
        int i = blockIdx.x * 256 + threadIdx.x;   // 512*256 == S*64 exactly
        int s = i >> 6, d = i & 63;
        float freq = powf(10000.0f, -(2.0f * (float)d) / 128.0f);
        float ang = (float)s * freq;
        cosT[i] = cosf(ang);
        sinT[i] = sinf(ang);
        return;
    }
    const float* s;
    __bf16* d;
    int n8;
    switch (blockIdx.y) {
        case 0: s = s0; d = d0; n8 = (B_SZ * S_LEN * DMODEL) / 8; break;      // qkv
        case 1: s = s1; d = d1; n8 = (DMODEL * DMODEL) / 8; break;            // Wq
        case 2: s = s2; d = d2; n8 = (NKV * DHEAD * DMODEL) / 8; break;       // Wk
        case 3: s = s3; d = d3; n8 = (NKV * DHEAD * DMODEL) / 8; break;       // Wv
        default: s = s4; d = d4; n8 = (DMODEL * DMODEL) / 8; break;           // Wo
    }
    for (int i = blockIdx.x * 256 + threadIdx.x; i < n8; i += 512 * 256) {
        float4 a = ((const float4*)s)[2 * i];
        float4 b = ((const float4*)s)[2 * i + 1];
        bf16x8 o = {(__bf16)a.x, (__bf16)a.y, (__bf16)a.z, (__bf16)a.w,
                    (__bf16)b.x, (__bf16)b.y, (__bf16)b.z, (__bf16)b.w};
        *(bf16x8*)&d[i * 8] = o;
    }
}

// ---------------------------------------------------------------------------
// 256-wide-tile GEMM mainloop, BK=64, 8 waves (2M x 4N), counted-vmcnt
// prefetch (distance 2), T2 XOR-swizzled LDS, 4-phase per-tile schedule.
// ---------------------------------------------------------------------------
template <int BM>
__device__ __forceinline__ void gemm256(const __bf16* __restrict__ A,
                                        const __bf16* __restrict__ W,
                                        int bm, int bn, int K,
                                        f32x4 (&acc)[BM / 32][4],
                                        __bf16* arena) {
    constexpr int MI = BM / 32;       // 8 (qkv) or 4 (out_proj)
    constexpr int ALT = BM / 64;      // stageA issues per thread
    constexpr int QM = MI / 4;        // mi per quad: 2 or 1
    __bf16* As = arena;                      // [2][BM*64]
    __bf16* Bs = arena + 2 * BM * 64;        // [2][256*64]
    const int tid = threadIdx.x;
    const int lane = tid & 63;
    const int wave = tid >> 6;
    const int lr = lane & 15, lk = lane >> 4;
    const int wr = wave >> 2;
    const int wc = wave & 3;
    const int sRow = lane >> 3;
    const int sCol = 8 * ((lane & 7) ^ sRow);

    auto stageA = [&](int bi, int k0) {
#pragma unroll
        for (int it = 0; it < ALT; ++it) {
            const int row = it * 64 + wave * 8 + sRow;
            gload_lds16(A + (size_t)(bm + row) * K + k0 + sCol,
                        As + bi * BM * 64 + it * 4096 + wave * 512);
        }
    };
    auto stageB = [&](int bi, int k0) {
#pragma unroll
        for (int it = 0; it < 4; ++it) {
            const int row = it * 64 + wave * 8 + sRow;
            gload_lds16(W + (size_t)(bn + row) * K + k0 + sCol,
                        Bs + bi * 16384 + it * 4096 + wave * 512);
        }
    };

#pragma unroll
    for (int mi = 0; mi < MI; ++mi)
#pragma unroll
        for (int ni = 0; ni < 4; ++ni) acc[mi][ni] = (f32x4){0.f, 0.f, 0.f, 0.f};

    const int NT = K >> 6;
    stageA(0, 0);
    stageB(0, 0);
    stageA(1, 64);
    stageB(1, 64);
    if constexpr (BM == 256) asm volatile("s_waitcnt vmcnt(8)" ::: "memory");
    else                     asm volatile("s_waitcnt vmcnt(6)" ::: "memory");
    __builtin_amdgcn_s_barrier();

    for (int t = 0; t < NT; ++t) {
        const int bi = t & 1;
        bf16x8 af[MI][2], bfr[4][2];
        auto rdA = [&](int i, int kk) {
            const int r = wr * (BM / 2) + i * 16 + lr;
            const int slot = (kk * 4 + lk) ^ (r & 7);
            af[i][kk] = *(const bf16x8*)&As[bi * BM * 64 + r * 64 + slot * 8];
        };
        auto quad = [&](int q) {
            __builtin_amdgcn_s_setprio(1);
#pragma unroll
            for (int mi = q * QM; mi < (q + 1) * QM; ++mi)
#pragma unroll
                for (int kk = 0; kk < 2; ++kk)
#pragma unroll
                    for (int ni = 0; ni < 4; ++ni)
                        acc[mi][ni] = MFMA(af[mi][kk], bfr[ni][kk], acc[mi][ni]);
            __builtin_amdgcn_s_setprio(0);
        };

        // ---- ph0: all B frags + quad0's A frags
#pragma unroll
        for (int i = 0; i < 4; ++i)
#pragma unroll
            for (int kk = 0; kk < 2; ++kk) {
                const int r = wc * 64 + i * 16 + lr;
                const int slot = (kk * 4 + lk) ^ (r & 7);
                bfr[i][kk] = *(const bf16x8*)&Bs[bi * 16384 + r * 64 + slot * 8];
            }
#pragma unroll
        for (int i = 0; i < QM; ++i)
#pragma unroll
            for (int kk = 0; kk < 2; ++kk) rdA(i, kk);
        __builtin_amdgcn_s_barrier();
        asm volatile("s_waitcnt lgkmcnt(0)" ::: "memory");
        __builtin_amdgcn_sched_barrier(0);
        quad(0);
        __builtin_amdgcn_s_barrier();

        // ---- ph1: remaining A frags
#pragma unroll
        for (int i = QM; i < MI; ++i)
#pragma unroll
            for (int kk = 0; kk < 2; ++kk) rdA(i, kk);
        __builtin_amdgcn_s_barrier();
        asm volatile("s_waitcnt lgkmcnt(0)" ::: "memory");
        __builtin_amdgcn_sched_barrier(0);
        quad(1);
        __builtin_amdgcn_s_barrier();
        // all waves' reads of buf[bi] are complete past this point

        // ---- ph2: stage A of tile t+2 into buf[bi]  ||  quad2 (regs only)
        if (t + 2 < NT) stageA(bi, (t + 2) * 64);
        quad(2);
        __builtin_amdgcn_s_barrier();

        // ---- ph3: stage B of tile t+2  ||  quad3; then publish t+1
        if (t + 2 < NT) stageB(bi, (t + 2) * 64);
        quad(3);
        if (t + 1 < NT) {
            if (t + 2 < NT) {
                if constexpr (BM == 256) asm volatile("s_waitcnt vmcnt(8)" ::: "memory");
                else                     asm volatile("s_waitcnt vmcnt(6)" ::: "memory");
            } else {
                asm volatile("s_waitcnt vmcnt(0)" ::: "memory");
            }
            __builtin_amdgcn_s_barrier();  // buf[(t+1)&1] ready for everyone
        }
    }
}

// ---------------------------------------------------------------------------
// Fused QKV projection: 256^2 GEMM + RMSNorm + RoPE (+SCALE for Q) + direct
// bf16 layout transforms.  grid 192 blocks (XCD-remapped), 512 threads.
// ---------------------------------------------------------------------------
__global__ __launch_bounds__(512, 2) void qkv_proj_kernel(
    const __bf16* __restrict__ qkvb, const __bf16* __restrict__ Wq,
    const __bf16* __restrict__ Wk, const __bf16* __restrict__ Wv,
    const float* __restrict__ qg, const float* __restrict__ kg,
    const float* __restrict__ cosT, const float* __restrict__ sinT,
    __bf16* __restrict__ qb, __bf16* __restrict__ kb, __bf16* __restrict__ vt) {
    __shared__ alignas(16) __bf16 arena[4 * 256 * 64];   // 128 KB
    const int id = (blockIdx.x & 7) * 24 + (blockIdx.x >> 3);  // bijective 192=8*24
    const int bmi = id / 12, bni = id % 12;
    const int bm = bmi * 256;
    const __bf16* W;
    int bn;
    if (bni < 8)       { W = Wq; bn = bni * 256; }
    else if (bni < 10) { W = Wk; bn = (bni - 8) * 256; }
    else               { W = Wv; bn = (bni - 10) * 256; }

    f32x4 acc[8][4];
    gemm256<256>(qkvb, W, bm, bn, 2048, acc, arena);
    // mainloop's final s_barrier synchronized all waves; arena is reusable.

    const int tid = threadIdx.x;
    const int lane = tid & 63, wave = tid >> 6;
    const int lr = lane & 15, lk = lane >> 4;
    const int wr = wave >> 2, wc = wave & 3;
    const int dc0 = (wc & 1) * 64;          // this wave's dcol base in head

    if (bni < 10) {
        // ---- Q or K: RMSNorm + RoPE ----
        const bool isQ = (bni < 8);
        const float* gamma = isQ ? qg : kg;
        const float scl = isQ ? SCALE : 1.0f;
        const int hh = (isQ ? bni * 2 : (bni - 8) * 2) + (wc >> 1);
        const int nh = isQ ? NHEADS : NKV;
        __bf16* outb = isQ ? qb : kb;
        float g[4];
#pragma unroll
        for (int ni = 0; ni < 4; ++ni) g[ni] = gamma[dc0 + ni * 16 + lr];

        float* xbuf = (float*)arena;                       // [512][33] = 67.6KB
        float* ssbuf = (float*)((char*)arena + 70 * 1024); // [4][256] = 4KB

        // Phase A: per-row sum of squares (64-col partial -> pair total)
        float rs[8][4];
#pragma unroll
        for (int mi = 0; mi < 8; ++mi)
#pragma unroll
            for (int r = 0; r < 4; ++r) {
                float ss = 0.f;
#pragma unroll
                for (int ni = 0; ni < 4; ++ni) ss += acc[mi][ni][r] * acc[mi][ni][r];
                ss += __shfl_xor(ss, 1);
                ss += __shfl_xor(ss, 2);
                ss += __shfl_xor(ss, 4);
                ss += __shfl_xor(ss, 8);
                if (lr == 0) ssbuf[wc * 256 + wr * 128 + mi * 16 + lk * 4 + r] = ss;
            }
        __syncthreads();
#pragma unroll
        for (int mi = 0; mi < 8; ++mi)
#pragma unroll
            for (int r = 0; r < 4; ++r) {
                const int rowl = wr * 128 + mi * 16 + lk * 4 + r;
                const float tot = ssbuf[wc * 256 + rowl] + ssbuf[(wc ^ 1) * 256 + rowl];
                rs[mi][r] = rsqrtf(tot * (1.0f / 128.0f) + 1e-6f) * scl;
            }
        __syncthreads();   // ssbuf reads done before xbuf writes (overlap-safe)

        // Phase B: chunked pair-exchange of normalized values + RoPE + store.
#pragma unroll
        for (int ch = 0; ch < 4; ++ch) {
            float y[2][4][4];
#pragma unroll
            for (int m2 = 0; m2 < 2; ++m2)
#pragma unroll
                for (int ni = 0; ni < 4; ++ni)
#pragma unroll
                    for (int r = 0; r < 4; ++r) {
                        const int mi = ch * 2 + m2;
                        y[m2][ni][r] = acc[mi][ni][r] * rs[mi][r] * g[ni];
                        xbuf[tid * 33 + m2 * 16 + ni * 4 + r] = y[m2][ni][r];
                    }
            __syncthreads();
            float yp[2][4][4];
#pragma unroll
            for (int m2 = 0; m2 < 2; ++m2)
#pragma unroll
                for (int ni = 0; ni < 4; ++ni)
#pragma unroll
                    for (int r = 0; r < 4; ++r)
                        yp[m2][ni][r] = xbuf[(tid ^ 64) * 33 + m2 * 16 + ni * 4 + r];
#pragma unroll
            for (int m2 = 0; m2 < 2; ++m2)
#pragma unroll
                for (int r = 0; r < 4; ++r) {
                    const int mi = ch * 2 + m2;
                    const int gm = bm + wr * 128 + mi * 16 + lk * 4 + r;
                    const int bb = gm >> 11, s = gm & 2047;
                    const float* ct = cosT + s * 64;
                    const float* st = sinT + s * 64;
                    __bf16* orow = outb + (((size_t)(bb * nh + hh)) * S_LEN + s) * DHEAD;
#pragma unroll
                    for (int ni = 0; ni < 4; ++ni) {
                        const int dd = ni * 16 + lr;
                        const float c = ct[dd], sn = st[dd];
                        const float own = y[m2][ni][r], par = yp[m2][ni][r];
                        const float o = (wc & 1) ? (own * c + par * sn)
                                                 : (own * c - par * sn);
                        orow[dc0 + dd] = (__bf16)o;
                    }
                }
            __syncthreads();   // xbuf consumed before next chunk overwrites
        }
    } else {
        // ---- V: write transposed bf16 directly into vt [B,KV,Dh,S] ----
        const int kvh = (bni - 10) * 2 + (wc >> 1);
#pragma unroll
        for (int mi = 0; mi < 8; ++mi) {
            const int gm = bm + wr * 128 + mi * 16 + lk * 4;  // 4 consecutive s
            const int bb = gm >> 11, s0 = gm & 2047;
            __bf16* vbase = vt + ((size_t)(bb * NKV + kvh)) * DHEAD * S_LEN;
#pragma unroll
            for (int ni = 0; ni < 4; ++ni) {
                const int d = dc0 + ni * 16 + lr;
                bf16x4 pk = {(__bf16)acc[mi][ni][0], (__bf16)acc[mi][ni][1],
                             (__bf16)acc[mi][ni][2], (__bf16)acc[mi][ni][3]};
                *(bf16x4*)&vbase[(size_t)d * S_LEN + s0] = pk;
            }
        }
    }
}

// ---------------------------------------------------------------------------
// Output projection.  1D grid of 256 blocks (XCD-remapped), 512 threads.
// ---------------------------------------------------------------------------
__global__ __launch_bounds__(512, 2) void out_proj_kernel(
    const __bf16* __restrict__ att, const __bf16* __restrict__ Wo,
    float* __restrict__ out) {
    __shared__ alignas(16) __bf16 arena[2 * 128 * 64 + 2 * 256 * 64];  // 96 KB
    const int id = (blockIdx.x & 7) * 32 + (blockIdx.x >> 3);  // bijective 256=8*32
    const int bm = (id >> 3) * 128, bn = (id & 7) * 256;

    f32x4 acc[4][4];
    gemm256<128>(att, Wo, bm, bn, 2048, acc, arena);

    const int lane = threadIdx.x & 63, wave = threadIdx.x >> 6;
    const int lr = lane & 15, lk = lane >> 4;
    const int wr = wave >> 2, wc = wave & 3;
#pragma unroll
    for (int mi = 0; mi < 4; ++mi)
#pragma unroll
        for (int ni = 0; ni < 4; ++ni)
#pragma unroll
            for (int r = 0; r < 4; ++r) {
                const int row = bm + wr * 64 + mi * 16 + lk * 4 + r;
                const int col = bn + wc * 64 + ni * 16 + lr;
                out[(size_t)row * DMODEL + col] = acc[mi][ni][r];
            }
}

// ---------------------------------------------------------------------------
// Causal flash attention (round-13 champion form: KVB=32, dual-frag waves,
// sequential frag_steps, setprio around MFMA clusters).
// grid (B*H, 16), 256 threads = 4 waves; block = strips j and 31-j.
// ---------------------------------------------------------------------------
__global__ __launch_bounds__(256, 2) void flash_kernel(
    const __bf16* __restrict__ qb, const __bf16* __restrict__ kb,
    const __bf16* __restrict__ vt, __bf16* __restrict__ att) {
    __shared__ alignas(16) __bf16 K_lds[2][32 * 128];   // 8KB each
    __shared__ alignas(16) __bf16 V_lds[2][128 * 32];   // 8KB each
    __shared__ alignas(16) __bf16 p_lds[4][16][40];

    const int bh = blockIdx.x;
    const int b = bh >> 4, h = bh & 15, kv = h >> 2;
    const int j = blockIdx.y;  // 0..15
    const int lane = threadIdx.x & 63, wave = threadIdx.x >> 6;
    const int lr = lane & 15, lk = lane >> 4;

    const int qloB = j * 64 + wave * 16;
    const int qhiB = (31 - j) * 64 + wave * 16;
    const int ntL  = ((qloB + 15) >> 5) + 1;
    const int ntHw = ((qhiB + 15) >> 5) + 1;
    const int ntH  = 64 - 2 * j;

    const __bf16* Qp = qb + ((size_t)(b * NHEADS + h)) * S_LEN * DHEAD;
    const __bf16* Kp = kb + ((size_t)(b * NKV + kv)) * S_LEN * DHEAD;
    const __bf16* Vt = vt + ((size_t)(b * NKV + kv)) * DHEAD * S_LEN;

    bf16x8 qlo[4], qhi[4];
#pragma unroll
    for (int f = 0; f < 4; ++f) {
        qlo[f] = *(const bf16x8*)&Qp[(size_t)(qloB + lr) * DHEAD + f * 32 + lk * 8];
        qhi[f] = *(const bf16x8*)&Qp[(size_t)(qhiB + lr) * DHEAD + f * 32 + lk * 8];
    }

    const int c0 = 2 * wave;
    const int l4 = lane >> 4, l15 = lane & 15;
    const int l2 = lane >> 2, l3 = lane & 3;
    const int vcol = ((l3 ^ (l2 & 3)) << 3);

    auto stage = [&](int bufi, int t) {
        const int k0s = t * KVB;
#pragma unroll
        for (int i = 0; i < 2; ++i) {
            const int c = c0 + i;
            const int rK = c * 4 + l4;
            const int kcol = ((l15 ^ (rK & 7)) << 3);
            gload_lds16(Kp + (size_t)(k0s + rK) * DHEAD + kcol, &K_lds[bufi][c * 512]);
            const int rV = c * 16 + l2;
            gload_lds16(Vt + (size_t)rV * S_LEN + k0s + vcol, &V_lds[bufi][c * 512]);
        }
    };

    f32x4 accL[8] = {}, accH[8] = {};
    float lsumL[4] = {0.f, 0.f, 0.f, 0.f}, lsumH[4] = {0.f, 0.f, 0.f, 0.f};
    const int swzK = (lr & 7) << 4;
    const int swzV = (lr & 3) << 4;

    auto frag_step = [&](const bf16x8 (&qf)[4], int qbase, f32x4 (&acc)[8],
                         float (&lsum)[4], const bf16x8 (&kf)[8],
                         const bf16x8 (&vf)[8], int k0) {
        f32x4 sc[2] = {};
        __builtin_amdgcn_s_setprio(1);
#pragma unroll
        for (int kk = 0; kk < 2; ++kk)
#pragma unroll
            for (int f = 0; f < 4; ++f)
                sc[kk] = MFMA(qf[f], kf[kk * 4 + f], sc[kk]);
        __builtin_amdgcn_s_setprio(0);
        asm volatile("s_waitcnt lgkmcnt(0)" ::: "memory");
#pragma unroll
        for (int r = 0; r < 4; ++r) {
            const int qr = qbase + lk * 4 + r;
            float s0 = sc[0][r], s1 = sc[1][r];
            if (k0 + lr > qr) s0 = -1e30f;
            if (k0 + 16 + lr > qr) s1 = -1e30f;
            float p0 = __expf(s0), p1 = __expf(s1);
            lsum[r] += p0 + p1;
            p_lds[wave][lk * 4 + r][lr] = (__bf16)p0;
            p_lds[wave][lk * 4 + r][lr + 16] = (__bf16)p1;
        }
        asm volatile("s_waitcnt lgkmcnt(0)" ::: "memory");
        bf16x8 pf = *(const bf16x8*)&p_lds[wave][lr][lk * 8];
        __builtin_amdgcn_s_setprio(1);
#pragma unroll
        for (int nf = 0; nf < 8; ++nf)
            acc[nf] = MFMA(pf, vf[nf], acc[nf]);
        __builtin_amdgcn_s_setprio(0);
    };

    int cur = 0;
    stage(0, 0);
    __syncthreads();
    for (int t = 0; t < ntH; ++t) {
        if (t + 1 < ntH) stage(cur ^ 1, t + 1);
        const int k0 = t * KVB;
        bf16x8 kf[8], vf[8];
#pragma unroll
        for (int kk = 0; kk < 2; ++kk)
#pragma unroll
            for (int f = 0; f < 4; ++f) {
                const int cb = (f * 64 + lk * 16) ^ swzK;
                kf[kk * 4 + f] =
                    *(const bf16x8*)((const char*)&K_lds[cur][(kk * 16 + lr) * 128] + cb);
            }
#pragma unroll
        for (int nf = 0; nf < 8; ++nf) {
            const int cb = (lk * 16) ^ swzV;
            vf[nf] = *(const bf16x8*)((const char*)&V_lds[cur][(nf * 16 + lr) * 32] + cb);
        }
        if (t < ntHw) frag_step(qhi, qhiB, accH, lsumH, kf, vf, k0);
        if (t < ntL)  frag_step(qlo, qloB, accL, lsumL, kf, vf, k0);
        __syncthreads();
        cur ^= 1;
    }

#pragma unroll
    for (int r = 0; r < 4; ++r) {
#pragma unroll
        for (int m = 1; m < 16; m <<= 1) {
            lsumL[r] += __shfl_xor(lsumL[r], m);
            lsumH[r] += __shfl_xor(lsumH[r], m);
        }
    }
#pragma unroll
    for (int nf = 0; nf < 8; ++nf)
#pragma unroll
        for (int r = 0; r < 4; ++r) {
            int qrL = qloB + lk * 4 + r;
            int qrH = qhiB + lk * 4 + r;
            att[((size_t)(b * S_LEN) + qrL) * DMODEL + h * DHEAD + nf * 16 + lr] =
                (__bf16)(accL[nf][r] / lsumL[r]);
            att[((size_t)(b * S_LEN) + qrH) * DMODEL + h * DHEAD + nf * 16 + lr] =
                (__bf16)(accH[nf][r] / lsumH[r]);
        }
}

// ---------------------------------------------------------------------------
extern "C" void kernel_launch(void* const* d_in, const int* in_sizes, int n_in,
                              void* d_out, int out_size, void* d_ws, size_t ws_size,
                              hipStream_t stream) {
    const float* qkv = (const float*)d_in[0];
    const float* Wq  = (const float*)d_in[1];
    const float* Wk  = (const float*)d_in[2];
    const float* Wv  = (const float*)d_in[3];
    const float* Wo  = (const float*)d_in[4];
    const float* qg  = (const float*)d_in[5];
    const float* kg  = (const float*)d_in[6];
    float* out = (float*)d_out;

    size_t off = 0;
    char* wsb = (char*)d_ws;
    auto alloc = [&](size_t n) {
        char* p = wsb + off;
        off += (n + 255) & ~(size_t)255;
        return (void*)p;
    };
    const size_t M = (size_t)B_SZ * S_LEN;  // 4096
    float* cosT   = (float*)alloc((size_t)S_LEN * 64 * 4);
    float* sinT   = (float*)alloc((size_t)S_LEN * 64 * 4);
    __bf16* qb    = (__bf16*)alloc((size_t)B_SZ * NHEADS * S_LEN * DHEAD * 2);
    __bf16* kb    = (__bf16*)alloc((size_t)B_SZ * NKV * S_LEN * DHEAD * 2);
    __bf16* vt    = (__bf16*)alloc((size_t)B_SZ * NKV * DHEAD * S_LEN * 2);
    __bf16* att   = (__bf16*)alloc(M * DMODEL * 2);
    __bf16* qkv_b = (__bf16*)alloc(M * DMODEL * 2);
    __bf16* wq_b  = (__bf16*)alloc((size_t)DMODEL * DMODEL * 2);
    __bf16* wk_b  = (__bf16*)alloc((size_t)NKV * DHEAD * DMODEL * 2);
    __bf16* wv_b  = (__bf16*)alloc((size_t)NKV * DHEAD * DMODEL * 2);
    __bf16* wo_b  = (__bf16*)alloc((size_t)DMODEL * DMODEL * 2);

    convert_kernel<<<dim3(512, 6), 256, 0, stream>>>(qkv, Wq, Wk, Wv, Wo,
                                                     qkv_b, wq_b, wk_b, wv_b, wo_b,
                                                     cosT, sinT);
    qkv_proj_kernel<<<192, 512, 0, stream>>>(qkv_b, wq_b, wk_b, wv_b,
                                             qg, kg, cosT, sinT, qb, kb, vt);
    flash_kernel<<<dim3(B_SZ * NHEADS, 16), 256, 0, stream>>>(qb, kb, vt, att);
    out_proj_kernel<<<256, 512, 0, stream>>>(att, wo_b, out);
}